// Round 2
// baseline (156.693 us; speedup 1.0000x reference)
//
#include <hip/hip_runtime.h>

// 9x9 clipped box-SUM on (8,3,1024,1024) f32, fused single pass, float4/lane.
// Wave = 64 lanes x 4 cols = 256 columns (248 outputs + 4-wide halo each side).
// Vertical: per-lane rolling float4 window sum (register ring, unroll-9).
// Horizontal: out[k] = sfx_left[k] + T + pfx_right[k] -- 8 independent shuffles,
// 2-deep add chain (vs 4 chained shuffles in round 1).

constexpr int H = 1024, W = 1024;
constexpr int RAD = 4;
constexpr int OUTW = 248;           // (64 lanes - 2 halo lanes) * 4 cols
constexpr int NSTRIP = 5;           // ceil(1024 / 248)
constexpr int CHUNK = 32;
constexpr int NCHUNK = H / CHUNK;   // 32
constexpr int NIMG = 24;            // 8 * 3

__global__ __launch_bounds__(256) void box9_kernel(const float* __restrict__ x,
                                                   float* __restrict__ out) {
    const int lane = threadIdx.x & 63;
    const int wid  = blockIdx.x * 4 + (threadIdx.x >> 6);

    const int chunk = wid & (NCHUNK - 1);       // NCHUNK = 32 (pow2)
    const int t     = wid >> 5;
    const int strip = t % NSTRIP;
    const int img   = t / NSTRIP;

    const int  cs  = strip * OUTW - RAD + lane * 4;   // first col this lane holds
    const bool cok = (cs >= 0) && (cs + 3 < W);       // full float4 in range (always aligned)
    const float* xp = x   + (size_t)img * (H * W) + (cok ? cs : 0);
    float*       op = out + (size_t)img * (H * W) + (cok ? cs : 0);

    const int h0 = chunk * CHUNK;
    const int h1 = h0 + CHUNK;

    // Warm-up: ring holds rows h0-4 .. h0+4 for this lane's 4 cols; V = vertical sums.
    float4 ring[9];
    float4 V = make_float4(0.f, 0.f, 0.f, 0.f);
#pragma unroll
    for (int j = 0; j < 9; ++j) {
        const int row = h0 - RAD + j;
        float4 v = make_float4(0.f, 0.f, 0.f, 0.f);
        if (cok && row >= 0 && row < H)
            v = *reinterpret_cast<const float4*>(xp + (size_t)row * W);
        ring[j] = v;
        V.x += v.x; V.y += v.y; V.z += v.z; V.w += v.w;
    }

    const bool sok = cok && (lane >= 1) && (lane <= 62);  // halo lanes don't store

    int h = h0;
    while (h < h1) {
        // Prefetch the next 9 rows (h+5 .. h+13) this group consumes.
        float4 nxt[9];
#pragma unroll
        for (int u = 0; u < 9; ++u) {
            const int row = h + RAD + 1 + u;
            nxt[u] = (cok && row < H && (h + u) < h1)
                   ? *reinterpret_cast<const float4*>(xp + (size_t)row * W)
                   : make_float4(0.f, 0.f, 0.f, 0.f);
        }
#pragma unroll
        for (int u = 0; u < 9; ++u) {
            if (h >= h1) break;
            // Own prefix/suffix sums of V (3-deep).
            const float p0 = V.x, p1 = p0 + V.y, p2 = p1 + V.z, T = p2 + V.w;
            const float s3 = V.w, s2 = s3 + V.z, s1 = s2 + V.y;   // sfx[0] = T
            // 8 INDEPENDENT shuffles: suffixes from left lane, prefixes from right.
            const float L0 = __shfl(T,  lane - 1);
            const float L1 = __shfl(s1, lane - 1);
            const float L2 = __shfl(s2, lane - 1);
            const float L3 = __shfl(s3, lane - 1);
            const float R0 = __shfl(p0, lane + 1);
            const float R1 = __shfl(p1, lane + 1);
            const float R2 = __shfl(p2, lane + 1);
            const float R3 = __shfl(T,  lane + 1);
            float4 o;
            o.x = L0 + T + R0;   // cols cs..cs+3, 9-wide windows
            o.y = L1 + T + R1;
            o.z = L2 + T + R2;
            o.w = L3 + T + R3;
            if (sok) *reinterpret_cast<float4*>(op + (size_t)h * W) = o;
            // Roll vertical window: add row h+5, drop row h-4.
            V.x += nxt[u].x - ring[u].x;
            V.y += nxt[u].y - ring[u].y;
            V.z += nxt[u].z - ring[u].z;
            V.w += nxt[u].w - ring[u].w;
            ring[u] = nxt[u];
            ++h;
        }
    }
}

extern "C" void kernel_launch(void* const* d_in, const int* in_sizes, int n_in,
                              void* d_out, int out_size, void* d_ws, size_t ws_size,
                              hipStream_t stream) {
    const float* x   = (const float*)d_in[0];
    float*       out = (float*)d_out;
    const int n_waves  = NIMG * NSTRIP * NCHUNK;   // 24*5*32 = 3840
    const int n_blocks = n_waves / 4;              // 960 blocks of 4 waves
    box9_kernel<<<dim3(n_blocks), dim3(256), 0, stream>>>(x, out);
}

// Round 3
// 59.270 us; speedup vs baseline: 2.6437x; 2.6437x over previous
//
#include <hip/hip_runtime.h>

// 9x9 clipped box-SUM on (8,3,1024,1024) f32, fused single pass, float4/lane.
// Wave = 64 lanes x 4 cols = 256 columns (248 outputs + 4-col halo each side).
// Vertical: rolling window sum V over rows [h-4, h+4]; updated by
//   V += x[h+5] - x[h-4]  (re-reading the dropped row -- it's L2/L3-resident;
//   the full 96 MB input fits in the 256 MB Infinity Cache).
//   NO register arrays -> no scratch-spill risk (round-2 lesson: ring[9]
//   arrays were demoted to local memory -> 300 MB of scratch HBM traffic).
// Horizontal: out[k] = sfx_left[k] + T + pfx_right[k] -- 8 independent
//   shuffles, 2-deep add chain.

constexpr int H = 1024, W = 1024;
constexpr int RAD = 4;
constexpr int OUTW = 248;           // (64 lanes - 2 halo lanes) * 4 cols
constexpr int NSTRIP = 5;           // ceil(1024 / 248)
constexpr int CHUNK = 16;
constexpr int NCHUNK = H / CHUNK;   // 64
constexpr int NIMG = 24;            // 8 * 3

__global__ __launch_bounds__(256) void box9_kernel(const float* __restrict__ x,
                                                   float* __restrict__ out) {
    const int lane = threadIdx.x & 63;
    const int wid  = blockIdx.x * 4 + (threadIdx.x >> 6);

    const int chunk = wid & (NCHUNK - 1);       // NCHUNK = 64 (pow2)
    const int t     = wid >> 6;
    const int strip = t % NSTRIP;
    const int img   = t / NSTRIP;

    const int  cs  = strip * OUTW - RAD + lane * 4;   // first col this lane holds
    const bool cok = (cs >= 0) && (cs + 3 < W);       // full float4 in range (aligned)
    const float* xp = x   + (size_t)img * (H * W) + (cok ? cs : 0);
    float*       op = out + (size_t)img * (H * W) + (cok ? cs : 0);

    const int h0 = chunk * CHUNK;
    const int h1 = h0 + CHUNK;

    auto ld = [&](int row) -> float4 {
        if (cok && (unsigned)row < (unsigned)H)
            return *reinterpret_cast<const float4*>(xp + (size_t)row * W);
        return make_float4(0.f, 0.f, 0.f, 0.f);
    };

    // Warm-up: V = sum of rows h0-4 .. h0+4 (clipped) for this lane's 4 cols.
    float4 V = make_float4(0.f, 0.f, 0.f, 0.f);
#pragma unroll
    for (int j = 0; j < 9; ++j) {
        const float4 v = ld(h0 - RAD + j);
        V.x += v.x; V.y += v.y; V.z += v.z; V.w += v.w;
    }

    const bool sok = cok && (lane >= 1) && (lane <= 62);  // halo lanes don't store

#pragma unroll 4
    for (int h = h0; h < h1; ++h) {
        // Loads for the V update are independent of the shuffle work below;
        // issue them first so they overlap the horizontal pass.
        const float4 a = ld(h + RAD + 1);   // row entering the window
        const float4 b = ld(h - RAD);       // row leaving the window (L2/L3 hit)

        // Own prefix/suffix sums of V (3-deep).
        const float p0 = V.x, p1 = p0 + V.y, p2 = p1 + V.z, T = p2 + V.w;
        const float s3 = V.w, s2 = s3 + V.z, s1 = s2 + V.y;
        // 8 INDEPENDENT shuffles: suffixes from left lane, prefixes from right.
        const float L0 = __shfl(T,  lane - 1);
        const float L1 = __shfl(s1, lane - 1);
        const float L2 = __shfl(s2, lane - 1);
        const float L3 = __shfl(s3, lane - 1);
        const float R0 = __shfl(p0, lane + 1);
        const float R1 = __shfl(p1, lane + 1);
        const float R2 = __shfl(p2, lane + 1);
        const float R3 = __shfl(T,  lane + 1);
        float4 o;
        o.x = L0 + T + R0;   // 9-wide windows for cols cs..cs+3
        o.y = L1 + T + R1;
        o.z = L2 + T + R2;
        o.w = L3 + T + R3;
        if (sok) *reinterpret_cast<float4*>(op + (size_t)h * W) = o;

        // Roll vertical window: add row h+5, drop row h-4.
        V.x += a.x - b.x;
        V.y += a.y - b.y;
        V.z += a.z - b.z;
        V.w += a.w - b.w;
    }
}

extern "C" void kernel_launch(void* const* d_in, const int* in_sizes, int n_in,
                              void* d_out, int out_size, void* d_ws, size_t ws_size,
                              hipStream_t stream) {
    const float* x   = (const float*)d_in[0];
    float*       out = (float*)d_out;
    const int n_waves  = NIMG * NSTRIP * NCHUNK;   // 24*5*64 = 7680
    const int n_blocks = n_waves / 4;              // 1920 blocks of 4 waves
    box9_kernel<<<dim3(n_blocks), dim3(256), 0, stream>>>(x, out);
}

// Round 4
// 39.376 us; speedup vs baseline: 3.9794x; 1.5052x over previous
//
#include <hip/hip_runtime.h>

// 9x9 clipped box-SUM on (8,3,1024,1024) f32 — fused, float4/lane,
// whole-chunk register staging for maximal memory-level parallelism.
//
// Wave = 64 lanes x 4 cols = 256 columns (248 outputs + 4-col halo/side).
// Each wave owns a 16-row chunk: loads ALL 25 needed rows (16 + 9 halo)
// into registers up front (25 independent global_load_dwordx4 in flight),
// then runs a pure-register rolling vertical sum + shuffle horizontal pass.
// All r[] indices are compile-time after full unroll (rule #20: no breaks,
// no runtime indexing -> no scratch demotion; verify via WRITE_SIZE ~ 97MB).

constexpr int H = 1024, W = 1024;
constexpr int RAD = 4;
constexpr int OUTW = 248;               // (64 - 2 halo lanes) * 4 cols
constexpr int NSTRIP = 5;               // ceil(1024 / 248)
constexpr int CHUNK = 16;
constexpr int NCHUNK = H / CHUNK;       // 64
constexpr int NIMG = 24;                // 8 * 3
constexpr int NROWS = CHUNK + 2 * RAD + 1;  // 25

__global__ __launch_bounds__(256) void box9_kernel(const float* __restrict__ x,
                                                   float* __restrict__ out) {
    const int lane = threadIdx.x & 63;
    const int wid  = blockIdx.x * 4 + (threadIdx.x >> 6);

    const int chunk = wid & (NCHUNK - 1);       // consecutive wids -> adjacent
    const int t     = wid >> 6;                 // chunks (halo rows L2/L3-hot)
    const int strip = t % NSTRIP;
    const int img   = t / NSTRIP;

    const int  cs  = strip * OUTW - RAD + lane * 4;   // first col this lane holds
    const bool cok = (cs >= 0) && (cs + 3 < W);       // float4 always 16B-aligned
    const float* xp = x   + (size_t)img * (H * W) + (cok ? cs : 0);
    float*       op = out + (size_t)img * (H * W) + (cok ? cs : 0);

    const int h0 = chunk * CHUNK;

    // Stage the whole chunk (+ vertical halo) in registers: 25 independent
    // loads issued before any compute waits on them.
    float4 r[NROWS];
#pragma unroll
    for (int j = 0; j < NROWS; ++j) {
        const int row = h0 - RAD + j;
        r[j] = (cok && (unsigned)row < (unsigned)H)
             ? *reinterpret_cast<const float4*>(xp + (size_t)row * W)
             : make_float4(0.f, 0.f, 0.f, 0.f);
    }

    // V = vertical 9-row window sum, initialized over rows h0-4 .. h0+4.
    float4 V = make_float4(0.f, 0.f, 0.f, 0.f);
#pragma unroll
    for (int j = 0; j < 9; ++j) {
        V.x += r[j].x; V.y += r[j].y; V.z += r[j].z; V.w += r[j].w;
    }

    const bool sok = cok && (lane >= 1) && (lane <= 62);  // halo lanes don't store

#pragma unroll
    for (int j = 0; j < CHUNK; ++j) {
        // Own prefix/suffix sums of V (3-deep).
        const float p0 = V.x, p1 = p0 + V.y, p2 = p1 + V.z, T = p2 + V.w;
        const float s3 = V.w, s2 = s3 + V.z, s1 = s2 + V.y;
        // 8 INDEPENDENT shuffles: suffixes from left lane, prefixes from right.
        const float L0 = __shfl(T,  lane - 1);
        const float L1 = __shfl(s1, lane - 1);
        const float L2 = __shfl(s2, lane - 1);
        const float L3 = __shfl(s3, lane - 1);
        const float R0 = __shfl(p0, lane + 1);
        const float R1 = __shfl(p1, lane + 1);
        const float R2 = __shfl(p2, lane + 1);
        const float R3 = __shfl(T,  lane + 1);
        float4 o;
        o.x = L0 + T + R0;   // 9-wide horizontal windows for cols cs..cs+3
        o.y = L1 + T + R1;
        o.z = L2 + T + R2;
        o.w = L3 + T + R3;
        if (sok) *reinterpret_cast<float4*>(op + (size_t)(h0 + j) * W) = o;

        // Roll vertical window: add row h0+j+5, drop row h0+j-4 (static idx).
        V.x += r[j + 9].x - r[j].x;
        V.y += r[j + 9].y - r[j].y;
        V.z += r[j + 9].z - r[j].z;
        V.w += r[j + 9].w - r[j].w;
    }
}

extern "C" void kernel_launch(void* const* d_in, const int* in_sizes, int n_in,
                              void* d_out, int out_size, void* d_ws, size_t ws_size,
                              hipStream_t stream) {
    const float* x   = (const float*)d_in[0];
    float*       out = (float*)d_out;
    const int n_waves  = NIMG * NSTRIP * NCHUNK;   // 24*5*64 = 7680
    const int n_blocks = n_waves / 4;              // 1920 blocks of 4 waves
    box9_kernel<<<dim3(n_blocks), dim3(256), 0, stream>>>(x, out);
}